// Round 9
// baseline (186.870 us; speedup 1.0000x reference)
//
#include <hip/hip_runtime.h>
#include <hip/hip_bf16.h>
#include <type_traits>

#define NB 8192
#define DD 256
#define INV_T (1.0f/0.07f)
#define LOG2E 1.4426950408889634f
#define K1    (INV_T*LOG2E)          // logit (log2 units) = acc*K1 - K1
#define CEXP  6.2087204553847255e-7f // exp(-1/0.07): folds the -K1 term into se
#define NSTRIP 64
#define TILE 128
#define BN 32
#define NITER 4              // 128 cols / 32
#define BUFB (BN*DD*2)       // 16384 bytes per LDS buffer
#define NTILES (NSTRIP*(NSTRIP+1)/2)   // 2080

typedef __attribute__((ext_vector_type(8))) short s8v;   // 8 bf16
typedef __attribute__((ext_vector_type(4))) float f4v;   // 4 f32 acc
typedef unsigned int u32;
typedef unsigned short u16;

// workspace layout (bytes)  (total ~8.3 MB)
#define OFF_FB   0                                  // bf16 normalized features: 4 MB
#define OFF_SE   (4*1024*1024)                      // f32 [64][8192] = 2 MB
#define OFF_SP   (OFF_SE + NSTRIP*NB*4)             // f32 [64][8192] = 2 MB
#define OFF_CL   (OFF_SP + NSTRIP*NB*4)             // f32[32]
#define OFF_CV   (OFF_CL + 256)                     // f32[32]
#define OFF_CNT  (OFF_CV + 256)                     // int[1]

// wave-per-row normalize: grid 2048 x 256 threads; block 0 zeros the finish counter
__global__ void k_norm(const float* __restrict__ feat,
                       __hip_bfloat16* __restrict__ fb, int* __restrict__ cnt) {
    if (blockIdx.x == 0 && threadIdx.x == 0) *cnt = 0;
    const int t = threadIdx.x;
    const int w = t >> 6, l = t & 63;
    const int row = blockIdx.x * 4 + w;
    const float4 v = ((const float4*)feat)[row * 64 + l];
    float s = v.x * v.x + v.y * v.y + v.z * v.z + v.w * v.w;
    #pragma unroll
    for (int d = 32; d; d >>= 1) s += __shfl_xor(s, d, 64);
    const float scale = 1.0f / fmaxf(sqrtf(s), 1e-12f);
    __hip_bfloat16 h0 = __float2bfloat16(v.x * scale);
    __hip_bfloat16 h1 = __float2bfloat16(v.y * scale);
    __hip_bfloat16 h2 = __float2bfloat16(v.z * scale);
    __hip_bfloat16 h3 = __float2bfloat16(v.w * scale);
    ushort4 o;
    o.x = *(u16*)&h0; o.y = *(u16*)&h1; o.z = *(u16*)&h2; o.w = *(u16*)&h3;
    ((ushort4*)fb)[row * 64 + l] = o;
}

__device__ __forceinline__ void gld16(const void* g, void* l) {
    __builtin_amdgcn_global_load_lds((const __attribute__((address_space(1))) u32*)g,
                                     (__attribute__((address_space(3))) u32*)l, 16, 0, 0);
}

// Symmetric fused sim + row/col reduction, 128x128 tiles, 4-deep residency.
// Grid = 2080 lower-triangle tiles (rb >= cb), cb-major. Off-diagonal tile computed
// once: row-sums -> strip[cb][rows of rb], col-sums -> strip[rb][cols of cb].
// Slot [k][i] (m=i>>7): k<m from tile(m,k) rows; k>m from tile(k,m) cols; k==m diag.
// Bijective -> no atomics.
__launch_bounds__(256, 4)
__global__ void k_main(const __hip_bfloat16* __restrict__ fb,
                       const int* __restrict__ lab,
                       float* __restrict__ SE, float* __restrict__ SP) {
    __shared__ __align__(16) char ldsB[2 * BUFB];   // 32 KB, XOR-swizzled
    __shared__ int ldsLab[TILE];                    // 512 B col labels
    __shared__ float ldsColE[4][BN];                // per-wave col sums (one iter slice)
    __shared__ float ldsColP[4][BN];
    __shared__ float colAccE[TILE];                 // accumulated col sums
    __shared__ float colAccP[TILE];
    const int tid = threadIdx.x;
    const int w = tid >> 6;
    const int l = tid & 63;
    const int l15 = l & 15, lg = l >> 4;

    // decode bid -> (rb, cb), cb-major lower triangle
    int cb = 0, rem = blockIdx.x;
    while (rem >= NSTRIP - cb) { rem -= NSTRIP - cb; cb++; }
    const int rb = cb + rem;
    const int row0 = rb * TILE, col0 = cb * TILE;
    const int wbase = row0 + w * 32;

    if (tid < TILE) {
        ldsLab[tid] = lab[col0 + tid];
        colAccE[tid] = 0.f;
        colAccP[tid] = 0.f;
    }

    // A fragments in registers: rows wbase + m*16 + l15, k = kk*32 + lg*8 + [0..7]
    s8v a[2][8];
    #pragma unroll
    for (int m = 0; m < 2; m++)
        #pragma unroll
        for (int kk = 0; kk < 8; kk++)
            a[m][kk] = *(const s8v*)(fb + (wbase + m * 16 + l15) * DD + kk * 32 + lg * 8);

    // labels of the 8 rows this lane accumulates
    int labr[8];
    #pragma unroll
    for (int m = 0; m < 2; m++)
        #pragma unroll
        for (int r = 0; r < 4; r++)
            labr[m * 4 + r] = lab[wbase + m * 16 + lg * 4 + r];

    float sE[8], sPa[8];
    #pragma unroll
    for (int i = 0; i < 8; i++) { sE[i] = 0.f; sPa[i] = 0.f; }

    // stage a 32x256 bf16 tile (16 KB) via global_load_lds:
    // linear LDS dest, inverse-swizzled global source (both-sides-or-neither)
    auto stage = [&](int ct, int bufoff) {
        const char* gt = (const char*)fb + (size_t)(col0 + ct * BN) * (DD * 2);
        #pragma unroll
        for (int i = 0; i < 4; i++) {
            const int x = i * 4096 + (tid << 4);    // linear LDS byte offset
            const int br = x >> 9;
            const int inrow = x & 511;
            gld16(gt + br * 512 + (inrow ^ ((br & 7) << 4)),
                  ldsB + bufoff + i * 4096 + w * 1024);
        }
    };

    auto run = [&](auto diagC) {
        constexpr bool DIAG = decltype(diagC)::value;
        stage(0, 0);
        __syncthreads();
        for (int ct = 0; ct < NITER; ct++) {
            const int curoff = (ct & 1) * BUFB;
            if (ct + 1 < NITER) stage(ct + 1, curoff ^ BUFB);

            const int lc0 = ldsLab[ct * BN + l15];
            const int lc1 = ldsLab[ct * BN + 16 + l15];

            f4v acc[2][2];
            #pragma unroll
            for (int m = 0; m < 2; m++) {
                acc[m][0] = (f4v){0.f, 0.f, 0.f, 0.f};
                acc[m][1] = (f4v){0.f, 0.f, 0.f, 0.f};
            }

            #pragma unroll
            for (int kk = 0; kk < 8; kk++) {
                const int br0 = l15, br1 = 16 + l15;
                s8v b0 = *(const s8v*)(ldsB + curoff + ((br0 * 512 + kk * 64 + lg * 16) ^ ((br0 & 7) << 4)));
                s8v b1 = *(const s8v*)(ldsB + curoff + ((br1 * 512 + kk * 64 + lg * 16) ^ ((br1 & 7) << 4)));
                acc[0][0] = __builtin_amdgcn_mfma_f32_16x16x32_bf16(a[0][kk], b0, acc[0][0], 0, 0, 0);
                acc[1][0] = __builtin_amdgcn_mfma_f32_16x16x32_bf16(a[1][kk], b0, acc[1][0], 0, 0, 0);
                acc[0][1] = __builtin_amdgcn_mfma_f32_16x16x32_bf16(a[0][kk], b1, acc[0][1], 0, 0, 0);
                acc[1][1] = __builtin_amdgcn_mfma_f32_16x16x32_bf16(a[1][kk], b1, acc[1][1], 0, 0, 0);
            }

            float cE[2] = {0.f, 0.f}, cP[2] = {0.f, 0.f};
            #pragma unroll
            for (int n = 0; n < 2; n++) {
                const int lcn = n ? lc1 : lc0;
                #pragma unroll
                for (int m = 0; m < 2; m++)
                    #pragma unroll
                    for (int r = 0; r < 4; r++) {
                        const int idx = m * 4 + r;
                        const float v = acc[m][n][r];
                        float e = exp2f(v * K1);          // true e = CEXP * this
                        bool pos = (lcn == labr[idx]);
                        if (DIAG) {
                            const int row = wbase + m * 16 + lg * 4 + r;
                            const int coln = col0 + ct * BN + n * 16 + l15;
                            const bool nself = (row != coln);
                            e = nself ? e : 0.f;
                            pos = pos && nself;
                        }
                        const float pv = pos ? v : 0.f;
                        sE[idx] += e;
                        sPa[idx] += pv;
                        if (!DIAG) { cE[n] += e; cP[n] += pv; }
                    }
            }

            if (!DIAG) {
                #pragma unroll
                for (int n = 0; n < 2; n++) {
                    cE[n] += __shfl_xor(cE[n], 16, 64);
                    cE[n] += __shfl_xor(cE[n], 32, 64);
                    cP[n] += __shfl_xor(cP[n], 16, 64);
                    cP[n] += __shfl_xor(cP[n], 32, 64);
                }
                if (l < 16) {
                    ldsColE[w][l15]      = cE[0];
                    ldsColE[w][16 + l15] = cE[1];
                    ldsColP[w][l15]      = cP[0];
                    ldsColP[w][16 + l15] = cP[1];
                }
            }
            __syncthreads();   // ldsCol visible; cur-buf reads done; prefetch drained
            if (!DIAG) {
                if (tid < BN) {
                    colAccE[ct * BN + tid] += ldsColE[0][tid] + ldsColE[1][tid]
                                            + ldsColE[2][tid] + ldsColE[3][tid];
                } else if (tid < 2 * BN) {
                    const int c = tid - BN;
                    colAccP[ct * BN + c] += ldsColP[0][c] + ldsColP[1][c]
                                          + ldsColP[2][c] + ldsColP[3][c];
                }
                __syncthreads();  // colAcc committed; ldsCol reusable next iter
            }
        }
    };
    if (rb == cb) run(std::true_type{}); else run(std::false_type{});

    // row-sums: reduce across the 16 lanes of each group -> strip[cb]
    #pragma unroll
    for (int idx = 0; idx < 8; idx++) {
        #pragma unroll
        for (int d = 1; d < 16; d <<= 1) {
            sE[idx]  += __shfl_xor(sE[idx], d, 16);
            sPa[idx] += __shfl_xor(sPa[idx], d, 16);
        }
    }
    if (l15 == 0) {
        #pragma unroll
        for (int idx = 0; idx < 8; idx++) {
            const int row = wbase + (idx >> 2) * 16 + lg * 4 + (idx & 3);
            SE[cb * NB + row] = sE[idx];
            SP[cb * NB + row] = sPa[idx];
        }
    }

    // col-sums -> strip[rb] (off-diagonal only); last in-loop barrier ordered colAcc
    if (rb != cb) {
        if (tid < TILE) SE[rb * NB + col0 + tid] = colAccE[tid];
        else            SP[rb * NB + col0 + (tid - TILE)] = colAccP[tid - TILE];
    }
}

// per-row finalize; 32 blocks of 256 (one 256-row chunk each).
// loss_row = log(se*CEXP + 1e-8) - (spa - n)*INV_T/n   [spa = sum_pos sim]
// Chunk fallback provably dead: CHUNK=256 > NUM_CLASSES=128.
__global__ void k_rows(const int* __restrict__ lab,
                       const float* __restrict__ SE, const float* __restrict__ SP,
                       float* __restrict__ CL, float* __restrict__ CV,
                       int* __restrict__ cnt, float* __restrict__ out) {
    __shared__ int h[128];
    const int t = threadIdx.x;
    if (t < 128) h[t] = 0;
    __syncthreads();
    #pragma unroll
    for (int i = 0; i < 32; i++)
        atomicAdd(&h[lab[t + i * 256]], 1);
    __syncthreads();

    const int row = blockIdx.x * 256 + t;
    float se = 0.f, spa = 0.f;
    #pragma unroll
    for (int s = 0; s < NSTRIP; s++) {
        se  += SE[s * NB + row];
        spa += SP[s * NB + row];
    }
    const int n = h[lab[row]] - 1;
    const float lse = logf(se * CEXP + 1e-8f);
    const bool valid = n > 0;
    float loss = valid ? (lse - (spa - (float)n) * INV_T / (float)n) : 0.f;
    float vf = valid ? 1.f : 0.f;
    #pragma unroll
    for (int d = 32; d; d >>= 1) { loss += __shfl_xor(loss, d, 64); vf += __shfl_xor(vf, d, 64); }
    __shared__ float pl[4], pv[4];
    __shared__ int isLast;
    if ((t & 63) == 0) { pl[t >> 6] = loss; pv[t >> 6] = vf; }
    __syncthreads();
    if (t == 0) {
        CL[blockIdx.x] = pl[0] + pl[1] + pl[2] + pl[3];
        CV[blockIdx.x] = pv[0] + pv[1] + pv[2] + pv[3];
        __threadfence();                       // release CL/CV
        isLast = (atomicAdd(cnt, 1) == 31);
    }
    __syncthreads();
    if (isLast) {
        __threadfence();                       // acquire others' CL/CV
        float lsum = (t < 32) ? CL[t] : 0.f;
        float vsum = (t < 32) ? CV[t] : 0.f;
        #pragma unroll
        for (int d = 32; d; d >>= 1) { lsum += __shfl_xor(lsum, d, 64); vsum += __shfl_xor(vsum, d, 64); }
        if (t == 0) {
            const float mean = lsum / (vsum + 1e-8f);
            out[0] = mean;   // loss (reduction == 'mean')
            out[1] = vsum;   // total_pairs
            out[2] = mean;   // mean_loss
        }
    }
}

extern "C" void kernel_launch(void* const* d_in, const int* in_sizes, int n_in,
                              void* d_out, int out_size, void* d_ws, size_t ws_size,
                              hipStream_t stream) {
    (void)in_sizes; (void)n_in; (void)out_size; (void)ws_size;
    const float* feat = (const float*)d_in[0];
    const int*   lab  = (const int*)d_in[1];
    char* ws = (char*)d_ws;
    __hip_bfloat16* fb = (__hip_bfloat16*)(ws + OFF_FB);
    float* SE = (float*)(ws + OFF_SE);
    float* SP = (float*)(ws + OFF_SP);
    float* CL = (float*)(ws + OFF_CL);
    float* CV = (float*)(ws + OFF_CV);
    int*   cnt = (int*)(ws + OFF_CNT);
    float* out = (float*)d_out;

    hipLaunchKernelGGL(k_norm, dim3(NB / 4), dim3(256), 0, stream, feat, fb, cnt);
    hipLaunchKernelGGL(k_main, dim3(NTILES), dim3(256), 0, stream, fb, lab, SE, SP);
    hipLaunchKernelGGL(k_rows, dim3(NB / 256), dim3(256), 0, stream, lab, SE, SP, CL, CV, cnt, out);
}

// Round 10
// 96.213 us; speedup vs baseline: 1.9423x; 1.9423x over previous
//
#include <hip/hip_runtime.h>
#include <hip/hip_bf16.h>
#include <type_traits>

#define NB 8192
#define DD 256
#define INV_T (1.0f/0.07f)
#define LOG2E 1.4426950408889634f
#define K1    (INV_T*LOG2E)          // logit (log2 units) = acc*K1 - K1
#define CEXP  6.2087204553847255e-7f // exp(-1/0.07): folds the -K1 term into se
#define NSTRIP 64
#define TILE 128
#define BN 32
#define NITER 4              // 128 cols / 32
#define BUFB (BN*DD*2)       // 16384 bytes per LDS buffer
#define NTILES (NSTRIP*(NSTRIP+1)/2)   // 2080

typedef __attribute__((ext_vector_type(8))) short s8v;   // 8 bf16
typedef __attribute__((ext_vector_type(4))) float f4v;   // 4 f32 acc
typedef unsigned int u32;
typedef unsigned short u16;

// workspace layout (bytes)  (total ~8.3 MB)
#define OFF_FB   0                                  // bf16 normalized features: 4 MB
#define OFF_SE   (4*1024*1024)                      // f32 [64][8192] = 2 MB
#define OFF_SP   (OFF_SE + NSTRIP*NB*4)             // f32 [64][8192] = 2 MB
#define OFF_CL   (OFF_SP + NSTRIP*NB*4)             // f32[32]
#define OFF_CV   (OFF_CL + 256)                     // f32[32]
#define OFF_CNT  (OFF_CV + 256)                     // int[1]

// wave-per-row normalize: grid 2048 x 256 threads; block 0 zeros the finish counter
__global__ void k_norm(const float* __restrict__ feat,
                       __hip_bfloat16* __restrict__ fb, int* __restrict__ cnt) {
    if (blockIdx.x == 0 && threadIdx.x == 0) *cnt = 0;
    const int t = threadIdx.x;
    const int w = t >> 6, l = t & 63;
    const int row = blockIdx.x * 4 + w;
    const float4 v = ((const float4*)feat)[row * 64 + l];
    float s = v.x * v.x + v.y * v.y + v.z * v.z + v.w * v.w;
    #pragma unroll
    for (int d = 32; d; d >>= 1) s += __shfl_xor(s, d, 64);
    const float scale = 1.0f / fmaxf(sqrtf(s), 1e-12f);
    __hip_bfloat16 h0 = __float2bfloat16(v.x * scale);
    __hip_bfloat16 h1 = __float2bfloat16(v.y * scale);
    __hip_bfloat16 h2 = __float2bfloat16(v.z * scale);
    __hip_bfloat16 h3 = __float2bfloat16(v.w * scale);
    ushort4 o;
    o.x = *(u16*)&h0; o.y = *(u16*)&h1; o.z = *(u16*)&h2; o.w = *(u16*)&h3;
    ((ushort4*)fb)[row * 64 + l] = o;
}

__device__ __forceinline__ void gld16(const void* g, void* l) {
    __builtin_amdgcn_global_load_lds((const __attribute__((address_space(1))) u32*)g,
                                     (__attribute__((address_space(3))) u32*)l, 16, 0, 0);
}

// Symmetric fused sim + row/col reduction, 128x128 tiles, 4-deep residency.
// Grid = 2080 lower-triangle tiles (rb >= cb), cb-major. Off-diagonal tile computed
// once: row-sums -> strip[cb][rows of rb], col-sums -> strip[rb][cols of cb].
// Slot [k][i] (m=i>>7): k<m from tile(m,k) rows; k>m from tile(k,m) cols; k==m diag.
// Bijective -> no atomics.
// NOTE: launch_bounds 2nd arg = 2 (VGPR cap 256). R9's (256,4) forced a 64-VGPR
// cap -> 228 MB scratch spill. Occupancy comes from LDS (35 KB -> 4 blocks/CU)
// and natural VGPR (~124 -> 4 waves/SIMD).
__launch_bounds__(256, 2)
__global__ void k_main(const __hip_bfloat16* __restrict__ fb,
                       const int* __restrict__ lab,
                       float* __restrict__ SE, float* __restrict__ SP) {
    __shared__ __align__(16) char ldsB[2 * BUFB];   // 32 KB, XOR-swizzled
    __shared__ int ldsLab[TILE];                    // 512 B col labels
    __shared__ float ldsColE[4][BN];                // per-wave col sums (one iter slice)
    __shared__ float ldsColP[4][BN];
    __shared__ float colAccE[TILE];                 // accumulated col sums
    __shared__ float colAccP[TILE];
    const int tid = threadIdx.x;
    const int w = tid >> 6;
    const int l = tid & 63;
    const int l15 = l & 15, lg = l >> 4;

    // decode bid -> (rb, cb), cb-major lower triangle
    int cb = 0, rem = blockIdx.x;
    while (rem >= NSTRIP - cb) { rem -= NSTRIP - cb; cb++; }
    const int rb = cb + rem;
    const int row0 = rb * TILE, col0 = cb * TILE;
    const int wbase = row0 + w * 32;

    if (tid < TILE) {
        ldsLab[tid] = lab[col0 + tid];
        colAccE[tid] = 0.f;
        colAccP[tid] = 0.f;
    }

    // A fragments in registers: rows wbase + m*16 + l15, k = kk*32 + lg*8 + [0..7]
    s8v a[2][8];
    #pragma unroll
    for (int m = 0; m < 2; m++)
        #pragma unroll
        for (int kk = 0; kk < 8; kk++)
            a[m][kk] = *(const s8v*)(fb + (wbase + m * 16 + l15) * DD + kk * 32 + lg * 8);

    // labels of the 8 rows this lane accumulates
    int labr[8];
    #pragma unroll
    for (int m = 0; m < 2; m++)
        #pragma unroll
        for (int r = 0; r < 4; r++)
            labr[m * 4 + r] = lab[wbase + m * 16 + lg * 4 + r];

    float sE[8], sPa[8];
    #pragma unroll
    for (int i = 0; i < 8; i++) { sE[i] = 0.f; sPa[i] = 0.f; }

    // stage a 32x256 bf16 tile (16 KB) via global_load_lds:
    // linear LDS dest, inverse-swizzled global source (both-sides-or-neither)
    auto stage = [&](int ct, int bufoff) {
        const char* gt = (const char*)fb + (size_t)(col0 + ct * BN) * (DD * 2);
        #pragma unroll
        for (int i = 0; i < 4; i++) {
            const int x = i * 4096 + (tid << 4);    // linear LDS byte offset
            const int br = x >> 9;
            const int inrow = x & 511;
            gld16(gt + br * 512 + (inrow ^ ((br & 7) << 4)),
                  ldsB + bufoff + i * 4096 + w * 1024);
        }
    };

    auto run = [&](auto diagC) {
        constexpr bool DIAG = decltype(diagC)::value;
        stage(0, 0);
        __syncthreads();
        for (int ct = 0; ct < NITER; ct++) {
            const int curoff = (ct & 1) * BUFB;
            if (ct + 1 < NITER) stage(ct + 1, curoff ^ BUFB);

            const int lc0 = ldsLab[ct * BN + l15];
            const int lc1 = ldsLab[ct * BN + 16 + l15];

            f4v acc[2][2];
            #pragma unroll
            for (int m = 0; m < 2; m++) {
                acc[m][0] = (f4v){0.f, 0.f, 0.f, 0.f};
                acc[m][1] = (f4v){0.f, 0.f, 0.f, 0.f};
            }

            #pragma unroll
            for (int kk = 0; kk < 8; kk++) {
                const int br0 = l15, br1 = 16 + l15;
                s8v b0 = *(const s8v*)(ldsB + curoff + ((br0 * 512 + kk * 64 + lg * 16) ^ ((br0 & 7) << 4)));
                s8v b1 = *(const s8v*)(ldsB + curoff + ((br1 * 512 + kk * 64 + lg * 16) ^ ((br1 & 7) << 4)));
                acc[0][0] = __builtin_amdgcn_mfma_f32_16x16x32_bf16(a[0][kk], b0, acc[0][0], 0, 0, 0);
                acc[1][0] = __builtin_amdgcn_mfma_f32_16x16x32_bf16(a[1][kk], b0, acc[1][0], 0, 0, 0);
                acc[0][1] = __builtin_amdgcn_mfma_f32_16x16x32_bf16(a[0][kk], b1, acc[0][1], 0, 0, 0);
                acc[1][1] = __builtin_amdgcn_mfma_f32_16x16x32_bf16(a[1][kk], b1, acc[1][1], 0, 0, 0);
            }

            float cE[2] = {0.f, 0.f}, cP[2] = {0.f, 0.f};
            #pragma unroll
            for (int n = 0; n < 2; n++) {
                const int lcn = n ? lc1 : lc0;
                #pragma unroll
                for (int m = 0; m < 2; m++)
                    #pragma unroll
                    for (int r = 0; r < 4; r++) {
                        const int idx = m * 4 + r;
                        const float v = acc[m][n][r];
                        float e = exp2f(v * K1);          // true e = CEXP * this
                        bool pos = (lcn == labr[idx]);
                        if (DIAG) {
                            const int row = wbase + m * 16 + lg * 4 + r;
                            const int coln = col0 + ct * BN + n * 16 + l15;
                            const bool nself = (row != coln);
                            e = nself ? e : 0.f;
                            pos = pos && nself;
                        }
                        const float pv = pos ? v : 0.f;
                        sE[idx] += e;
                        sPa[idx] += pv;
                        if (!DIAG) { cE[n] += e; cP[n] += pv; }
                    }
            }

            if (!DIAG) {
                #pragma unroll
                for (int n = 0; n < 2; n++) {
                    cE[n] += __shfl_xor(cE[n], 16, 64);
                    cE[n] += __shfl_xor(cE[n], 32, 64);
                    cP[n] += __shfl_xor(cP[n], 16, 64);
                    cP[n] += __shfl_xor(cP[n], 32, 64);
                }
                if (l < 16) {
                    ldsColE[w][l15]      = cE[0];
                    ldsColE[w][16 + l15] = cE[1];
                    ldsColP[w][l15]      = cP[0];
                    ldsColP[w][16 + l15] = cP[1];
                }
            }
            __syncthreads();   // ldsCol visible; cur-buf reads done; prefetch drained
            if (!DIAG) {
                if (tid < BN) {
                    colAccE[ct * BN + tid] += ldsColE[0][tid] + ldsColE[1][tid]
                                            + ldsColE[2][tid] + ldsColE[3][tid];
                } else if (tid < 2 * BN) {
                    const int c = tid - BN;
                    colAccP[ct * BN + c] += ldsColP[0][c] + ldsColP[1][c]
                                          + ldsColP[2][c] + ldsColP[3][c];
                }
                __syncthreads();  // colAcc committed; ldsCol reusable next iter
            }
        }
    };
    if (rb == cb) run(std::true_type{}); else run(std::false_type{});

    // row-sums: reduce across the 16 lanes of each group -> strip[cb]
    #pragma unroll
    for (int idx = 0; idx < 8; idx++) {
        #pragma unroll
        for (int d = 1; d < 16; d <<= 1) {
            sE[idx]  += __shfl_xor(sE[idx], d, 16);
            sPa[idx] += __shfl_xor(sPa[idx], d, 16);
        }
    }
    if (l15 == 0) {
        #pragma unroll
        for (int idx = 0; idx < 8; idx++) {
            const int row = wbase + (idx >> 2) * 16 + lg * 4 + (idx & 3);
            SE[cb * NB + row] = sE[idx];
            SP[cb * NB + row] = sPa[idx];
        }
    }

    // col-sums -> strip[rb] (off-diagonal only); last in-loop barrier ordered colAcc
    if (rb != cb) {
        if (tid < TILE) SE[rb * NB + col0 + tid] = colAccE[tid];
        else            SP[rb * NB + col0 + (tid - TILE)] = colAccP[tid - TILE];
    }
}

// per-row finalize; 32 blocks of 256 (one 256-row chunk each).
// loss_row = log(se*CEXP + 1e-8) - (spa - n)*INV_T/n   [spa = sum_pos sim]
// Chunk fallback provably dead: CHUNK=256 > NUM_CLASSES=128.
__global__ void k_rows(const int* __restrict__ lab,
                       const float* __restrict__ SE, const float* __restrict__ SP,
                       float* __restrict__ CL, float* __restrict__ CV,
                       int* __restrict__ cnt, float* __restrict__ out) {
    __shared__ int h[128];
    const int t = threadIdx.x;
    if (t < 128) h[t] = 0;
    __syncthreads();
    #pragma unroll
    for (int i = 0; i < 32; i++)
        atomicAdd(&h[lab[t + i * 256]], 1);
    __syncthreads();

    const int row = blockIdx.x * 256 + t;
    float se = 0.f, spa = 0.f;
    #pragma unroll
    for (int s = 0; s < NSTRIP; s++) {
        se  += SE[s * NB + row];
        spa += SP[s * NB + row];
    }
    const int n = h[lab[row]] - 1;
    const float lse = logf(se * CEXP + 1e-8f);
    const bool valid = n > 0;
    float loss = valid ? (lse - (spa - (float)n) * INV_T / (float)n) : 0.f;
    float vf = valid ? 1.f : 0.f;
    #pragma unroll
    for (int d = 32; d; d >>= 1) { loss += __shfl_xor(loss, d, 64); vf += __shfl_xor(vf, d, 64); }
    __shared__ float pl[4], pv[4];
    __shared__ int isLast;
    if ((t & 63) == 0) { pl[t >> 6] = loss; pv[t >> 6] = vf; }
    __syncthreads();
    if (t == 0) {
        CL[blockIdx.x] = pl[0] + pl[1] + pl[2] + pl[3];
        CV[blockIdx.x] = pv[0] + pv[1] + pv[2] + pv[3];
        __threadfence();                       // release CL/CV
        isLast = (atomicAdd(cnt, 1) == 31);
    }
    __syncthreads();
    if (isLast) {
        __threadfence();                       // acquire others' CL/CV
        float lsum = (t < 32) ? CL[t] : 0.f;
        float vsum = (t < 32) ? CV[t] : 0.f;
        #pragma unroll
        for (int d = 32; d; d >>= 1) { lsum += __shfl_xor(lsum, d, 64); vsum += __shfl_xor(vsum, d, 64); }
        if (t == 0) {
            const float mean = lsum / (vsum + 1e-8f);
            out[0] = mean;   // loss (reduction == 'mean')
            out[1] = vsum;   // total_pairs
            out[2] = mean;   // mean_loss
        }
    }
}

extern "C" void kernel_launch(void* const* d_in, const int* in_sizes, int n_in,
                              void* d_out, int out_size, void* d_ws, size_t ws_size,
                              hipStream_t stream) {
    (void)in_sizes; (void)n_in; (void)out_size; (void)ws_size;
    const float* feat = (const float*)d_in[0];
    const int*   lab  = (const int*)d_in[1];
    char* ws = (char*)d_ws;
    __hip_bfloat16* fb = (__hip_bfloat16*)(ws + OFF_FB);
    float* SE = (float*)(ws + OFF_SE);
    float* SP = (float*)(ws + OFF_SP);
    float* CL = (float*)(ws + OFF_CL);
    float* CV = (float*)(ws + OFF_CV);
    int*   cnt = (int*)(ws + OFF_CNT);
    float* out = (float*)d_out;

    hipLaunchKernelGGL(k_norm, dim3(NB / 4), dim3(256), 0, stream, feat, fb, cnt);
    hipLaunchKernelGGL(k_main, dim3(NTILES), dim3(256), 0, stream, fb, lab, SE, SP);
    hipLaunchKernelGGL(k_rows, dim3(NB / 256), dim3(256), 0, stream, lab, SE, SP, CL, CV, cnt, out);
}

// Round 11
// 75.868 us; speedup vs baseline: 2.4631x; 1.2682x over previous
//
#include <hip/hip_runtime.h>
#include <hip/hip_bf16.h>
#include <type_traits>

#define NB 8192
#define DD 256
#define INV_T (1.0f/0.07f)
#define LOG2E 1.4426950408889634f
#define K1    (INV_T*LOG2E)          // logit (log2 units) = acc*K1 - K1
#define CEXP  6.2087204553847255e-7f // exp(-1/0.07): folds the -K1 term into se
#define NSTRIP 32
#define TILE 256
#define BN 64
#define NITER 4              // 256 cols / 64
#define BUFB (BN*DD*2)       // 32768 bytes per LDS buffer
#define NTILES (NSTRIP*(NSTRIP+1)/2)   // 528

typedef __attribute__((ext_vector_type(8))) short s8v;   // 8 bf16
typedef __attribute__((ext_vector_type(4))) float f4v;   // 4 f32 acc
typedef unsigned int u32;
typedef unsigned short u16;

// workspace layout (bytes)
#define OFF_FB   0                                  // bf16 normalized features: 4 MB
#define OFF_SE   (4*1024*1024)                      // f32 [32][8192] = 1 MB
#define OFF_SP   (OFF_SE + NSTRIP*NB*4)             // f32 [32][8192] = 1 MB
#define OFF_CL   (OFF_SP + NSTRIP*NB*4)             // f32[32]
#define OFF_CV   (OFF_CL + 256)                     // f32[32]
#define OFF_CNT  (OFF_CV + 256)                     // int[1]

__device__ __forceinline__ u32 packEP(float e, float p) {
    __hip_bfloat16 be = __float2bfloat16(e), bp = __float2bfloat16(p);
    return (u32)*(u16*)&be | ((u32)*(u16*)&bp << 16);
}
__device__ __forceinline__ float unpLo(u32 x) {
    u16 h = (u16)x; __hip_bfloat16 b = *(__hip_bfloat16*)&h; return __bfloat162float(b);
}
__device__ __forceinline__ float unpHi(u32 x) {
    u16 h = (u16)(x >> 16); __hip_bfloat16 b = *(__hip_bfloat16*)&h; return __bfloat162float(b);
}

// wave-per-row normalize: grid 2048 x 256 threads; block 0 zeros the finish counter
__global__ void k_norm(const float* __restrict__ feat,
                       __hip_bfloat16* __restrict__ fb, int* __restrict__ cnt) {
    if (blockIdx.x == 0 && threadIdx.x == 0) *cnt = 0;
    const int t = threadIdx.x;
    const int w = t >> 6, l = t & 63;
    const int row = blockIdx.x * 4 + w;
    const float4 v = ((const float4*)feat)[row * 64 + l];
    float s = v.x * v.x + v.y * v.y + v.z * v.z + v.w * v.w;
    #pragma unroll
    for (int d = 32; d; d >>= 1) s += __shfl_xor(s, d, 64);
    const float scale = 1.0f / fmaxf(sqrtf(s), 1e-12f);
    __hip_bfloat16 h0 = __float2bfloat16(v.x * scale);
    __hip_bfloat16 h1 = __float2bfloat16(v.y * scale);
    __hip_bfloat16 h2 = __float2bfloat16(v.z * scale);
    __hip_bfloat16 h3 = __float2bfloat16(v.w * scale);
    ushort4 o;
    o.x = *(u16*)&h0; o.y = *(u16*)&h1; o.z = *(u16*)&h2; o.w = *(u16*)&h3;
    ((ushort4*)fb)[row * 64 + l] = o;
}

__device__ __forceinline__ void gld16(const void* g, void* l) {
    __builtin_amdgcn_global_load_lds((const __attribute__((address_space(1))) u32*)g,
                                     (__attribute__((address_space(3))) u32*)l, 16, 0, 0);
}

// Symmetric fused sim + row/col reduction; 256x256 tiles, 528 blocks, 2 blocks/CU.
// One barrier per iter; per-wave-per-iter col partials in packed bf16x2 LDS slots
// (no cross-wave phase in loop). Row-sums -> strip[cb][rows of rb]; col-sums ->
// strip[rb][cols of cb]. Bijective slot routing -> no atomics.
__launch_bounds__(512)
__global__ void k_main(const __hip_bfloat16* __restrict__ fb,
                       const int* __restrict__ lab,
                       float* __restrict__ SE, float* __restrict__ SP) {
    __shared__ __align__(16) char ldsB[2 * BUFB];   // 64 KB, XOR-swizzled
    __shared__ int ldsLab[TILE];                    // 1 KB col labels
    __shared__ u32 ldsCol[8][NITER][BN];            // 8 KB packed (bf16 E | bf16 P)
    const int tid = threadIdx.x;
    const int w = tid >> 6;
    const int l = tid & 63;
    const int l15 = l & 15, lg = l >> 4;

    // decode bid -> (rb, cb), cb-major lower triangle
    int cb = 0, rem = blockIdx.x;
    while (rem >= NSTRIP - cb) { rem -= NSTRIP - cb; cb++; }
    const int rb = cb + rem;
    const int row0 = rb * TILE, col0 = cb * TILE;
    const int wbase = row0 + w * 32;

    if (tid < TILE) ldsLab[tid] = lab[col0 + tid];

    // A fragments in registers: rows wbase + m*16 + l15, k = kk*32 + lg*8 + [0..7]
    s8v a[2][8];
    #pragma unroll
    for (int m = 0; m < 2; m++)
        #pragma unroll
        for (int kk = 0; kk < 8; kk++)
            a[m][kk] = *(const s8v*)(fb + (wbase + m * 16 + l15) * DD + kk * 32 + lg * 8);

    // labels of the 8 rows this lane accumulates
    int labr[8];
    #pragma unroll
    for (int m = 0; m < 2; m++)
        #pragma unroll
        for (int r = 0; r < 4; r++)
            labr[m * 4 + r] = lab[wbase + m * 16 + lg * 4 + r];

    float sE[8], sPa[8];
    #pragma unroll
    for (int i = 0; i < 8; i++) { sE[i] = 0.f; sPa[i] = 0.f; }

    // stage a 64x256 bf16 tile (32 KB) via global_load_lds:
    // linear LDS dest (wave-uniform base + lane*16), inverse-swizzled global source
    auto stage = [&](int ct, int bufoff) {
        const char* gt = (const char*)fb + (size_t)(col0 + ct * BN) * (DD * 2);
        #pragma unroll
        for (int i = 0; i < 4; i++) {
            const int x = i * 8192 + (tid << 4);    // linear LDS byte offset
            const int br = x >> 9;
            const int inrow = x & 511;
            gld16(gt + br * 512 + (inrow ^ ((br & 7) << 4)),
                  ldsB + bufoff + i * 8192 + w * 1024);
        }
    };

    auto run = [&](auto diagC) {
        constexpr bool DIAG = decltype(diagC)::value;
        stage(0, 0);
        __syncthreads();
        for (int ct = 0; ct < NITER; ct++) {
            const int curoff = (ct & 1) * BUFB;
            if (ct + 1 < NITER) stage(ct + 1, curoff ^ BUFB);

            int lc[4];
            #pragma unroll
            for (int n = 0; n < 4; n++)
                lc[n] = ldsLab[ct * BN + n * 16 + l15];

            f4v acc[2][4];
            #pragma unroll
            for (int m = 0; m < 2; m++)
                #pragma unroll
                for (int n = 0; n < 4; n++)
                    acc[m][n] = (f4v){0.f, 0.f, 0.f, 0.f};

            #pragma unroll
            for (int kk = 0; kk < 8; kk++) {
                s8v bfr[4];
                #pragma unroll
                for (int n = 0; n < 4; n++) {
                    const int br = n * 16 + l15;
                    const int ad = (br * 512 + kk * 64 + lg * 16) ^ ((br & 7) << 4);
                    bfr[n] = *(const s8v*)(ldsB + curoff + ad);
                }
                #pragma unroll
                for (int m = 0; m < 2; m++)
                    #pragma unroll
                    for (int n = 0; n < 4; n++)
                        acc[m][n] = __builtin_amdgcn_mfma_f32_16x16x32_bf16(a[m][kk], bfr[n], acc[m][n], 0, 0, 0);
            }

            float cE[4], cP[4];
            #pragma unroll
            for (int n = 0; n < 4; n++) { cE[n] = 0.f; cP[n] = 0.f; }
            #pragma unroll
            for (int n = 0; n < 4; n++) {
                #pragma unroll
                for (int m = 0; m < 2; m++)
                    #pragma unroll
                    for (int r = 0; r < 4; r++) {
                        const int idx = m * 4 + r;
                        const float v = acc[m][n][r];
                        float e = exp2f(v * K1);          // true e = CEXP * this
                        bool pos = (lc[n] == labr[idx]);
                        if (DIAG) {
                            const int row = wbase + m * 16 + lg * 4 + r;
                            const int coln = col0 + ct * BN + n * 16 + l15;
                            const bool nself = (row != coln);
                            e = nself ? e : 0.f;
                            pos = pos && nself;
                        }
                        const float pv = pos ? v : 0.f;
                        sE[idx] += e;
                        sPa[idx] += pv;
                        if (!DIAG) { cE[n] += e; cP[n] += pv; }
                    }
            }

            if (!DIAG) {
                // butterfly over the 4 lane-groups -> full col partial in every lane
                #pragma unroll
                for (int n = 0; n < 4; n++) {
                    cE[n] += __shfl_xor(cE[n], 16, 64);
                    cE[n] += __shfl_xor(cE[n], 32, 64);
                    cP[n] += __shfl_xor(cP[n], 16, 64);
                    cP[n] += __shfl_xor(cP[n], 32, 64);
                }
                if (l < 16) {
                    #pragma unroll
                    for (int n = 0; n < 4; n++)
                        ldsCol[w][ct][n * 16 + l15] = packEP(cE[n], cP[n]);
                }
            }
            __syncthreads();   // cur-buf reads done; prefetch drained; col slots ordered
        }
    };
    if (rb == cb) run(std::true_type{}); else run(std::false_type{});

    // row-sums: reduce across the 16 lanes of each group -> strip[cb]
    #pragma unroll
    for (int idx = 0; idx < 8; idx++) {
        #pragma unroll
        for (int d = 1; d < 16; d <<= 1) {
            sE[idx]  += __shfl_xor(sE[idx], d, 16);
            sPa[idx] += __shfl_xor(sPa[idx], d, 16);
        }
    }
    if (l15 == 0) {
        #pragma unroll
        for (int idx = 0; idx < 8; idx++) {
            const int row = wbase + (idx >> 2) * 16 + lg * 4 + (idx & 3);
            SE[cb * NB + row] = sE[idx];
            SP[cb * NB + row] = sPa[idx];
        }
    }

    // col-sums: combine the 8 waves' packed slots -> strip[rb] (off-diagonal only)
    if (rb != cb && tid < TILE) {
        const int ct = tid >> 6, j = tid & 63;
        float e = 0.f, p = 0.f;
        #pragma unroll
        for (int w2 = 0; w2 < 8; w2++) {
            const u32 x = ldsCol[w2][ct][j];
            e += unpLo(x);
            p += unpHi(x);
        }
        SE[rb * NB + col0 + tid] = e;
        SP[rb * NB + col0 + tid] = p;
    }
}

// per-row finalize; 32 blocks of 256 (one 256-row chunk each).
// loss_row = log(se*CEXP + 1e-8) - (spa - n)*INV_T/n   [spa = sum_pos sim]
// Chunk fallback provably dead: CHUNK=256 > NUM_CLASSES=128.
__global__ void k_rows(const int* __restrict__ lab,
                       const float* __restrict__ SE, const float* __restrict__ SP,
                       float* __restrict__ CL, float* __restrict__ CV,
                       int* __restrict__ cnt, float* __restrict__ out) {
    __shared__ int h[128];
    const int t = threadIdx.x;
    if (t < 128) h[t] = 0;
    __syncthreads();
    #pragma unroll
    for (int i = 0; i < 32; i++)
        atomicAdd(&h[lab[t + i * 256]], 1);
    __syncthreads();

    const int row = blockIdx.x * 256 + t;
    float se = 0.f, spa = 0.f;
    #pragma unroll
    for (int s = 0; s < NSTRIP; s++) {
        se  += SE[s * NB + row];
        spa += SP[s * NB + row];
    }
    const int n = h[lab[row]] - 1;
    const float lse = logf(se * CEXP + 1e-8f);
    const bool valid = n > 0;
    float loss = valid ? (lse - (spa - (float)n) * INV_T / (float)n) : 0.f;
    float vf = valid ? 1.f : 0.f;
    #pragma unroll
    for (int d = 32; d; d >>= 1) { loss += __shfl_xor(loss, d, 64); vf += __shfl_xor(vf, d, 64); }
    __shared__ float pl[4], pv[4];
    __shared__ int isLast;
    if ((t & 63) == 0) { pl[t >> 6] = loss; pv[t >> 6] = vf; }
    __syncthreads();
    if (t == 0) {
        CL[blockIdx.x] = pl[0] + pl[1] + pl[2] + pl[3];
        CV[blockIdx.x] = pv[0] + pv[1] + pv[2] + pv[3];
        __threadfence();                       // release CL/CV
        isLast = (atomicAdd(cnt, 1) == 31);
    }
    __syncthreads();
    if (isLast) {
        __threadfence();                       // acquire others' CL/CV
        float lsum = (t < 32) ? CL[t] : 0.f;
        float vsum = (t < 32) ? CV[t] : 0.f;
        #pragma unroll
        for (int d = 32; d; d >>= 1) { lsum += __shfl_xor(lsum, d, 64); vsum += __shfl_xor(vsum, d, 64); }
        if (t == 0) {
            const float mean = lsum / (vsum + 1e-8f);
            out[0] = mean;   // loss (reduction == 'mean')
            out[1] = vsum;   // total_pairs
            out[2] = mean;   // mean_loss
        }
    }
}

extern "C" void kernel_launch(void* const* d_in, const int* in_sizes, int n_in,
                              void* d_out, int out_size, void* d_ws, size_t ws_size,
                              hipStream_t stream) {
    (void)in_sizes; (void)n_in; (void)out_size; (void)ws_size;
    const float* feat = (const float*)d_in[0];
    const int*   lab  = (const int*)d_in[1];
    char* ws = (char*)d_ws;
    __hip_bfloat16* fb = (__hip_bfloat16*)(ws + OFF_FB);
    float* SE = (float*)(ws + OFF_SE);
    float* SP = (float*)(ws + OFF_SP);
    float* CL = (float*)(ws + OFF_CL);
    float* CV = (float*)(ws + OFF_CV);
    int*   cnt = (int*)(ws + OFF_CNT);
    float* out = (float*)d_out;

    hipLaunchKernelGGL(k_norm, dim3(NB / 4), dim3(256), 0, stream, feat, fb, cnt);
    hipLaunchKernelGGL(k_main, dim3(NTILES), dim3(512), 0, stream, fb, lab, SE, SP);
    hipLaunchKernelGGL(k_rows, dim3(NB / 256), dim3(256), 0, stream, lab, SE, SP, CL, CV, cnt, out);
}

// Round 12
// 71.639 us; speedup vs baseline: 2.6085x; 1.0590x over previous
//
#include <hip/hip_runtime.h>
#include <hip/hip_bf16.h>

#define NB 8192
#define DD 256
#define INV_T (1.0f/0.07f)
#define LOG2E 1.4426950408889634f
#define K1    (INV_T*LOG2E)          // logit (log2 units) = acc*K1 - K1
#define CEXP  6.2087204553847255e-7f // exp(-1/0.07): folds the -K1 term into se
#define NSTRIP 32
#define TILE 256
#define BN 64
#define BUFB (BN*DD*2)       // 32768 bytes per LDS buffer

typedef __attribute__((ext_vector_type(8))) short s8v;   // 8 bf16
typedef __attribute__((ext_vector_type(4))) float f4v;   // 4 f32 acc
typedef unsigned int u32;
typedef unsigned short u16;

// workspace layout (bytes)
#define OFF_FB   0                                  // bf16 normalized features: 4 MB
#define OFF_SEA  (4*1024*1024)                      // f32[8192] row-sum atomics
#define OFF_SPA  (OFF_SEA + NB*4)                   // f32[8192] (contiguous w/ SEA)
#define OFF_CE   (OFF_SPA + NB*4)                   // f32[32][8192] col-sum slots
#define OFF_CP   (OFF_CE + NSTRIP*NB*4)
#define OFF_CL   (OFF_CP + NSTRIP*NB*4)             // f32[32]
#define OFF_CV   (OFF_CL + 256)                     // f32[32]
#define OFF_CNT  (OFF_CV + 256)                     // int[1]

// wave-per-row normalize; blocks 0..63 also zero SEa/SPa (64 KB); block 0 zeros cnt
__global__ void k_norm(const float* __restrict__ feat,
                       __hip_bfloat16* __restrict__ fb,
                       float* __restrict__ SEa, int* __restrict__ cnt) {
    const int t = threadIdx.x;
    if (blockIdx.x == 0 && t == 0) *cnt = 0;
    if (blockIdx.x < 64) SEa[blockIdx.x * 256 + t] = 0.f;   // SEa+SPa contiguous 16384 f32
    const int w = t >> 6, l = t & 63;
    const int row = blockIdx.x * 4 + w;
    const float4 v = ((const float4*)feat)[row * 64 + l];
    float s = v.x * v.x + v.y * v.y + v.z * v.z + v.w * v.w;
    #pragma unroll
    for (int d = 32; d; d >>= 1) s += __shfl_xor(s, d, 64);
    const float scale = 1.0f / fmaxf(sqrtf(s), 1e-12f);
    __hip_bfloat16 h0 = __float2bfloat16(v.x * scale);
    __hip_bfloat16 h1 = __float2bfloat16(v.y * scale);
    __hip_bfloat16 h2 = __float2bfloat16(v.z * scale);
    __hip_bfloat16 h3 = __float2bfloat16(v.w * scale);
    ushort4 o;
    o.x = *(u16*)&h0; o.y = *(u16*)&h1; o.z = *(u16*)&h2; o.w = *(u16*)&h3;
    ((ushort4*)fb)[row * 64 + l] = o;
}

__device__ __forceinline__ void gld16(const void* g, void* l) {
    __builtin_amdgcn_global_load_lds((const __attribute__((address_space(1))) u32*)g,
                                     (__attribute__((address_space(3))) u32*)l, 16, 0, 0);
}

// Symmetric fused sim + row/col reduction — persistent balanced blocks.
// Pair p = (strip 31-s, strip s): exactly 132 64-col iters; 16 blocks/pair, 8-9 iters
// each; 256 blocks total, 1/CU, A-fragments amortized over the whole block.
// Row-sums -> f32 atomicAdd into SEa/SPa. Col-sums of iter (strip r, cols c0..c0+63)
// -> plain stores to CE/CP[r][cols] (exactly one writer per entry; entries for
// cols >= r*256 never written and never read). Diagonal 256-tiles: row path covers
// the full tile (self-masked), no col output.
__launch_bounds__(512)
__global__ void k_main(const __hip_bfloat16* __restrict__ fb,
                       const int* __restrict__ lab,
                       float* __restrict__ SEa, float* __restrict__ SPa,
                       float* __restrict__ CE, float* __restrict__ CP) {
    __shared__ __align__(16) char ldsB[2 * BUFB];   // 64 KB, XOR-swizzled
    __shared__ float ldsColE[8][BN];                // 2 KB per-wave col partials
    __shared__ float ldsColP[8][BN];                // 2 KB
    const int tid = threadIdx.x;
    const int w = tid >> 6;
    const int l = tid & 63;
    const int l15 = l & 15, lg = l >> 4;

    const int s = blockIdx.x >> 4;          // pair 0..15
    const int j = blockIdx.x & 15;          // block within pair
    const int nA = 4 * (32 - s);            // iters of strip A = 31-s
    const int cnt = 8 + (j >= 12 ? 1 : 0);  // 12x8 + 4x9 = 132
    const int off = 8 * j + (j > 12 ? j - 12 : 0);

    s8v a[2][8];
    int labr[8];
    int wbase = 0;
    auto loadA = [&](int r) {
        wbase = r * TILE + w * 32;
        #pragma unroll
        for (int m = 0; m < 2; m++)
            #pragma unroll
            for (int kk = 0; kk < 8; kk++)
                a[m][kk] = *(const s8v*)(fb + (wbase + m * 16 + l15) * DD + kk * 32 + lg * 8);
        #pragma unroll
        for (int m = 0; m < 2; m++)
            #pragma unroll
            for (int r2 = 0; r2 < 4; r2++)
                labr[m * 4 + r2] = lab[wbase + m * 16 + lg * 4 + r2];
    };

    float sE[8], sPa_[8];
    #pragma unroll
    for (int i = 0; i < 8; i++) { sE[i] = 0.f; sPa_[i] = 0.f; }
    auto flushRows = [&]() {
        #pragma unroll
        for (int idx = 0; idx < 8; idx++) {
            #pragma unroll
            for (int d = 1; d < 16; d <<= 1) {
                sE[idx]   += __shfl_xor(sE[idx], d, 16);
                sPa_[idx] += __shfl_xor(sPa_[idx], d, 16);
            }
        }
        if (l15 == 0) {
            #pragma unroll
            for (int idx = 0; idx < 8; idx++) {
                const int row = wbase + (idx >> 2) * 16 + lg * 4 + (idx & 3);
                atomicAdd(&SEa[row], sE[idx]);
                atomicAdd(&SPa[row], sPa_[idx]);
            }
        }
        #pragma unroll
        for (int i = 0; i < 8; i++) { sE[i] = 0.f; sPa_[i] = 0.f; }
    };

    // stage 64x256 bf16 tile of cols colOf(g): linear LDS dest, inv-swizzled source
    auto stage = [&](int g, int bufoff) {
        const int c0 = (g < nA ? g : g - nA) * 64;
        const char* gt = (const char*)fb + (size_t)c0 * (DD * 2);
        #pragma unroll
        for (int i = 0; i < 4; i++) {
            const int x = i * 8192 + (tid << 4);
            const int br = x >> 9;
            const int inrow = x & 511;
            gld16(gt + br * 512 + (inrow ^ ((br & 7) << 4)),
                  ldsB + bufoff + i * 8192 + w * 1024);
        }
    };

    stage(off, 0);
    loadA(off < nA ? 31 - s : s);
    __syncthreads();

    for (int t = 0; t < cnt; t++) {
        const int g = off + t;
        const int curoff = (t & 1) * BUFB;
        if (t + 1 < cnt) stage(g + 1, curoff ^ BUFB);

        const int r = (g < nA) ? 31 - s : s;
        const int i = (g < nA) ? g : g - nA;
        const int col0 = i * 64;
        const bool diag = ((i >> 2) == r);

        int lc[4];
        #pragma unroll
        for (int n = 0; n < 4; n++)
            lc[n] = lab[col0 + n * 16 + l15];

        f4v acc[2][4];
        #pragma unroll
        for (int m = 0; m < 2; m++)
            #pragma unroll
            for (int n = 0; n < 4; n++)
                acc[m][n] = (f4v){0.f, 0.f, 0.f, 0.f};

        #pragma unroll
        for (int kk = 0; kk < 8; kk++) {
            s8v bfr[4];
            #pragma unroll
            for (int n = 0; n < 4; n++) {
                const int br = n * 16 + l15;
                const int ad = (br * 512 + kk * 64 + lg * 16) ^ ((br & 7) << 4);
                bfr[n] = *(const s8v*)(ldsB + curoff + ad);
            }
            #pragma unroll
            for (int m = 0; m < 2; m++)
                #pragma unroll
                for (int n = 0; n < 4; n++)
                    acc[m][n] = __builtin_amdgcn_mfma_f32_16x16x32_bf16(a[m][kk], bfr[n], acc[m][n], 0, 0, 0);
        }

        float cE[4], cP[4];
        #pragma unroll
        for (int n = 0; n < 4; n++) { cE[n] = 0.f; cP[n] = 0.f; }
        #pragma unroll
        for (int n = 0; n < 4; n++) {
            #pragma unroll
            for (int m = 0; m < 2; m++)
                #pragma unroll
                for (int rr = 0; rr < 4; rr++) {
                    const int idx = m * 4 + rr;
                    const float v = acc[m][n][rr];
                    float e = exp2f(v * K1);          // true e = CEXP * this
                    bool pos = (lc[n] == labr[idx]);
                    if (diag) {
                        const int row = wbase + m * 16 + lg * 4 + rr;
                        const int coln = col0 + n * 16 + l15;
                        const bool nself = (row != coln);
                        e = nself ? e : 0.f;
                        pos = pos && nself;
                    }
                    const float pv = pos ? v : 0.f;
                    sE[idx] += e;
                    sPa_[idx] += pv;
                    cE[n] += e;
                    cP[n] += pv;
                }
        }

        if (!diag) {
            #pragma unroll
            for (int n = 0; n < 4; n++) {
                cE[n] += __shfl_xor(cE[n], 16, 64);
                cE[n] += __shfl_xor(cE[n], 32, 64);
                cP[n] += __shfl_xor(cP[n], 16, 64);
                cP[n] += __shfl_xor(cP[n], 32, 64);
            }
            if (l < 16) {
                #pragma unroll
                for (int n = 0; n < 4; n++) {
                    ldsColE[w][n * 16 + l15] = cE[n];
                    ldsColP[w][n * 16 + l15] = cP[n];
                }
            }
        }
        __syncthreads();   // col partials visible; cur-buf reads done; prefetch drained
        if (!diag && tid < BN) {
            float e = 0.f, p = 0.f;
            #pragma unroll
            for (int w2 = 0; w2 < 8; w2++) { e += ldsColE[w2][tid]; p += ldsColP[w2][tid]; }
            CE[r * NB + col0 + tid] = e;
            CP[r * NB + col0 + tid] = p;
        }
        __syncthreads();   // ldsCol reusable; safe to overwrite staged buffer next iter

        if (t + 1 < cnt && g + 1 == nA) {   // strip switch (at most once per block)
            flushRows();
            loadA(s);
        }
    }
    flushRows();
}

// per-row finalize; 32 blocks of 256 (block = one 256-row strip c0).
// se_total = SEa[row] + sum_{r>c0} CE[r][row]  (same for sp).
// loss_row = log(se*CEXP + 1e-8) - (spa - n)*INV_T/n
// Chunk fallback provably dead: CHUNK=256 > NUM_CLASSES=128.
__global__ void k_rows(const int* __restrict__ lab,
                       const float* __restrict__ SEa, const float* __restrict__ SPa,
                       const float* __restrict__ CE, const float* __restrict__ CP,
                       float* __restrict__ CL, float* __restrict__ CV,
                       int* __restrict__ cnt, float* __restrict__ out) {
    __shared__ int h[128];
    const int t = threadIdx.x;
    if (t < 128) h[t] = 0;
    __syncthreads();
    #pragma unroll
    for (int i = 0; i < 32; i++)
        atomicAdd(&h[lab[t + i * 256]], 1);
    __syncthreads();

    const int row = blockIdx.x * 256 + t;
    float se = SEa[row], spa = SPa[row];
    for (int r = blockIdx.x + 1; r < NSTRIP; r++) {
        se  += CE[r * NB + row];
        spa += CP[r * NB + row];
    }
    const int n = h[lab[row]] - 1;
    const float lse = logf(se * CEXP + 1e-8f);
    const bool valid = n > 0;
    float loss = valid ? (lse - (spa - (float)n) * INV_T / (float)n) : 0.f;
    float vf = valid ? 1.f : 0.f;
    #pragma unroll
    for (int d = 32; d; d >>= 1) { loss += __shfl_xor(loss, d, 64); vf += __shfl_xor(vf, d, 64); }
    __shared__ float pl[4], pv[4];
    __shared__ int isLast;
    if ((t & 63) == 0) { pl[t >> 6] = loss; pv[t >> 6] = vf; }
    __syncthreads();
    if (t == 0) {
        CL[blockIdx.x] = pl[0] + pl[1] + pl[2] + pl[3];
        CV[blockIdx.x] = pv[0] + pv[1] + pv[2] + pv[3];
        __threadfence();                       // release CL/CV
        isLast = (atomicAdd(cnt, 1) == 31);
    }
    __syncthreads();
    if (isLast) {
        __threadfence();                       // acquire others' CL/CV
        float lsum = (t < 32) ? CL[t] : 0.f;
        float vsum = (t < 32) ? CV[t] : 0.f;
        #pragma unroll
        for (int d = 32; d; d >>= 1) { lsum += __shfl_xor(lsum, d, 64); vsum += __shfl_xor(vsum, d, 64); }
        if (t == 0) {
            const float mean = lsum / (vsum + 1e-8f);
            out[0] = mean;   // loss (reduction == 'mean')
            out[1] = vsum;   // total_pairs
            out[2] = mean;   // mean_loss
        }
    }
}

extern "C" void kernel_launch(void* const* d_in, const int* in_sizes, int n_in,
                              void* d_out, int out_size, void* d_ws, size_t ws_size,
                              hipStream_t stream) {
    (void)in_sizes; (void)n_in; (void)out_size; (void)ws_size;
    const float* feat = (const float*)d_in[0];
    const int*   lab  = (const int*)d_in[1];
    char* ws = (char*)d_ws;
    __hip_bfloat16* fb = (__hip_bfloat16*)(ws + OFF_FB);
    float* SEa = (float*)(ws + OFF_SEA);
    float* SPa = (float*)(ws + OFF_SPA);
    float* CE  = (float*)(ws + OFF_CE);
    float* CP  = (float*)(ws + OFF_CP);
    float* CL  = (float*)(ws + OFF_CL);
    float* CV  = (float*)(ws + OFF_CV);
    int*   cnt = (int*)(ws + OFF_CNT);
    float* out = (float*)d_out;

    hipLaunchKernelGGL(k_norm, dim3(NB / 4), dim3(256), 0, stream, feat, fb, SEa, cnt);
    hipLaunchKernelGGL(k_main, dim3(256), dim3(512), 0, stream, fb, lab, SEa, SPa, CE, CP);
    hipLaunchKernelGGL(k_rows, dim3(NB / 256), dim3(256), 0, stream, lab, SEa, SPa, CE, CP, CL, CV, cnt, out);
}